// Round 8
// baseline (572.410 us; speedup 1.0000x reference)
//
#include <hip/hip_runtime.h>
#include <hip/hip_bf16.h>
#include <string.h>

typedef __hip_bfloat16 bf16;
typedef __attribute__((ext_vector_type(8))) short short8;
typedef __attribute__((ext_vector_type(4))) float floatx4;

#define Bn 8
#define Cc 128
#define Hh 128
#define Wl 128
#define HW (Hh*Wl)
#define NT (Bn*HW)   // 131072 tokens
#define REG 8388608  // elements per qkv phase-buffer (16 MiB bf16)

__device__ __forceinline__ float b2f(bf16 v){ return __bfloat162float(v); }
__device__ __forceinline__ bf16  f2b(float v){ return __float2bfloat16(v); }
__device__ __forceinline__ float s2f(short s){
  unsigned u = ((unsigned)(unsigned short)s) << 16;
  float f; memcpy(&f, &u, 4); return f;
}

// ---------------- all weight transposes in one launch ----------------
__global__ __launch_bounds__(256) void transpose_all(const float* __restrict__ wqkv,
                                                     const float* __restrict__ proj_w,
                                                     const float* __restrict__ fc1_w,
                                                     const float* __restrict__ fc2_w,
                                                     bf16* __restrict__ qkvT,
                                                     bf16* __restrict__ projT,
                                                     bf16* __restrict__ fc1T,
                                                     bf16* __restrict__ fc2T){
  int idx = blockIdx.x*256 + threadIdx.x;
  const float* src; bf16* dst; int K, N;
  if(idx < 49152){ src=wqkv; dst=qkvT; K=128; N=384; }
  else if(idx < 65536){ idx -= 49152; src=proj_w; dst=projT; K=128; N=128; }
  else if(idx < 131072){ idx -= 65536; src=fc1_w; dst=fc1T; K=128; N=512; }
  else { idx -= 131072; src=fc2_w; dst=fc2T; K=512; N=128; }
  int n = idx % N, k = idx / N;
  dst[(size_t)n*K + k] = f2b(src[idx]);
}

// ---------------- depthwise 3x3 conv + bias + residual -> channel-last fp32 ----------------
__global__ __launch_bounds__(256) void conv_kernel(const float* __restrict__ x,
                                                   const float* __restrict__ cw,
                                                   const float* __restrict__ cb,
                                                   float* __restrict__ xt){
  __shared__ float tile[16][132];
  int blk = blockIdx.x;              // ((b*8 + cg)*128 + h)
  int h = blk & 127; int t = blk >> 7;
  int cg = t & 7;    int b = t >> 3;
  int w4 = threadIdx.x & 31;
  int ci = threadIdx.x >> 5;
  int w0 = w4*4;
#pragma unroll
  for(int cc=0; cc<2; cc++){
    int c = cg*16 + ci*2 + cc;
    const float* xp = x + ((size_t)(b*Cc + c))*HW;
    float wg[9];
#pragma unroll
    for(int i=0;i<9;i++) wg[i] = cw[c*9+i];
    float4 rowv[3]; float lf[3], rt[3];
#pragma unroll
    for(int r=0;r<3;r++){
      int hh = h-1+r;
      float4 v = {0.f,0.f,0.f,0.f};
      if(hh>=0 && hh<Hh) v = *(const float4*)(xp + hh*Wl + w0);
      rowv[r] = v;
      float l = __shfl_up(v.w, 1, 32);
      float rr = __shfl_down(v.x, 1, 32);
      lf[r] = (w4==0)  ? 0.f : l;
      rt[r] = (w4==31) ? 0.f : rr;
    }
    float acc0 = cb[c], acc1 = cb[c], acc2 = cb[c], acc3 = cb[c];
#pragma unroll
    for(int r=0;r<3;r++){
      float4 v = rowv[r];
      acc0 += wg[r*3+0]*lf[r] + wg[r*3+1]*v.x + wg[r*3+2]*v.y;
      acc1 += wg[r*3+0]*v.x   + wg[r*3+1]*v.y + wg[r*3+2]*v.z;
      acc2 += wg[r*3+0]*v.y   + wg[r*3+1]*v.z + wg[r*3+2]*v.w;
      acc3 += wg[r*3+0]*v.z   + wg[r*3+1]*v.w + wg[r*3+2]*rt[r];
    }
    acc0 += rowv[1].x; acc1 += rowv[1].y; acc2 += rowv[1].z; acc3 += rowv[1].w;
    float4 o = {acc0, acc1, acc2, acc3};
    *(float4*)&tile[ci*2+cc][w0] = o;
  }
  __syncthreads();
  const size_t obase = ((size_t)b*HW + (size_t)h*Wl)*Cc + cg*16;
#pragma unroll
  for(int i=0;i<8;i++){
    int idx = i*256 + threadIdx.x;
    int c2 = idx & 15, w2 = idx >> 4;
    xt[obase + (size_t)w2*Cc + c2] = tile[c2][w2];
  }
}

// ---------------- LayerNorm over C=128, one wave per token ----------------
__global__ __launch_bounds__(256) void ln_kernel(const float* __restrict__ xt,
                                                 const float* __restrict__ wv,
                                                 const float* __restrict__ bv,
                                                 bf16* __restrict__ xn){
  int tok  = blockIdx.x*4 + (threadIdx.x>>6);
  int lane = threadIdx.x & 63;
  const float* row = xt + (size_t)tok*Cc;
  float v0 = row[lane], v1 = row[lane+64];
  float s = v0+v1;
#pragma unroll
  for(int off=32; off; off>>=1) s += __shfl_down(s, off, 64);
  s = __shfl(s, 0, 64);
  float m = s * (1.0f/128.0f);
  float d0 = v0-m, d1 = v1-m;
  float vs = d0*d0 + d1*d1;
#pragma unroll
  for(int off=32; off; off>>=1) vs += __shfl_down(vs, off, 64);
  vs = __shfl(vs, 0, 64);
  float rstd = rsqrtf(vs*(1.0f/128.0f) + 1e-5f);
  bf16* orow = xn + (size_t)tok*Cc;
  orow[lane]    = f2b(d0*rstd*wv[lane]    + bv[lane]);
  orow[lane+64] = f2b(d1*rstd*wv[lane+64] + bv[lane+64]);
}

// ---------------- MFMA bf16 GEMM ----------------
// EPI 0: qkv -> scatter into 6 head-major attention buffers (outb = base of qL..vG)
// EPI 1: +bias, GELU, bf16; EPI 2: +bias, xt += ls*v; EPI 3: +bias, bf16(xt + ls*v)
template<int EPI>
__global__ __launch_bounds__(256) void mfma_gemm(const bf16* __restrict__ A,
                                                 const bf16* __restrict__ Wt,
                                                 const float* __restrict__ bias,
                                                 bf16* __restrict__ outb,
                                                 float* __restrict__ xt,
                                                 const float* __restrict__ ls,
                                                 int N, int K){
  __shared__ short As[128*32];
  __shared__ short Bs[64*32];
  const int m0 = blockIdx.y*128, n0 = blockIdx.x*64;
  const int tid = threadIdx.x;
  const int lane = tid & 63;
  const int w = tid >> 6;

  floatx4 acc[4][2];
#pragma unroll
  for(int i=0;i<4;i++)
#pragma unroll
    for(int j=0;j<2;j++) acc[i][j] = (floatx4){0.f,0.f,0.f,0.f};

  for(int k0=0; k0<K; k0+=32){
#pragma unroll
    for(int p=0;p<2;p++){
      int ch = tid + p*256;
      int r = ch & 127, c = ch >> 7;
      short8 v = *(const short8*)(A + (size_t)(m0+r)*K + k0 + c*8);
      int lidx = ((r>>4)*4 + c)*16 + (r&15);
      *(short8*)&As[lidx*8] = v;
    }
    {
      int n = tid & 63, c = tid >> 6;
      short8 v = *(const short8*)(Wt + (size_t)(n0+n)*K + k0 + c*8);
      int lidx = ((n>>4)*4 + c)*16 + (n&15);
      *(short8*)&Bs[lidx*8] = v;
    }
    __syncthreads();
    short8 af[4], bfr[2];
#pragma unroll
    for(int mt=0;mt<4;mt++) af[mt] = *(short8*)&As[(((w&1)*4+mt)*64 + lane)*8];
#pragma unroll
    for(int nt=0;nt<2;nt++) bfr[nt] = *(short8*)&Bs[(((w>>1)*2+nt)*64 + lane)*8];
#pragma unroll
    for(int mt=0;mt<4;mt++)
#pragma unroll
      for(int nt=0;nt<2;nt++)
        acc[mt][nt] = __builtin_amdgcn_mfma_f32_16x16x32_bf16(af[mt], bfr[nt], acc[mt][nt], 0, 0, 0);
    __syncthreads();
  }

#pragma unroll
  for(int mt=0;mt<4;mt++){
#pragma unroll
    for(int nt=0;nt<2;nt++){
#pragma unroll
      for(int r=0;r<4;r++){
        int row = m0 + (w&1)*64 + mt*16 + ((lane>>4))*4 + r;
        int col = n0 + (w>>1)*32 + nt*16 + (lane&15);
        float v = acc[mt][nt][r];
        if(EPI==0){
          // scatter to attention layout: reg 0..5 = qL,qG,kL,kG,vL,vG
          int reg = col >> 6;
          int head = (col >> 4) & 3;
          int ch = col & 15;
          int b = row >> 14, h = (row >> 7) & 127, ww = row & 127;
          size_t didx;
          if(!(reg & 1)){
            int inst = ((b*16 + (h>>3))*16 + (ww>>3))*4 + head;
            int pos = (h&7)*8 + (ww&7);
            didx = ((size_t)inst*64 + pos)*16 + ch;
          } else {
            int inst = ((b*8 + (h&7))*8 + (ww&7))*4 + head;
            int pos = (h>>3)*16 + (ww>>3);
            didx = ((size_t)inst*256 + pos)*16 + ch;
          }
          outb[(size_t)reg*REG + didx] = f2b(v);
        } else if(EPI==1){
          v += bias[col];
          v = 0.5f*v*(1.0f + erff(v*0.70710678118f));
          outb[(size_t)row*N + col] = f2b(v);
        } else if(EPI==2){
          v += bias[col];
          xt[(size_t)row*128 + col] += ls[col]*v;
        } else {
          v += bias[col];
          float rr = xt[(size_t)row*128 + col] + ls[col]*v;
          outb[(size_t)row*128 + col] = f2b(rr);
        }
      }
    }
  }
}

#define SC2 0.36067376022224085f   // 0.25 * log2(e)

// ---------------- local attention: blk = winid*4 + head, L=64, fp8 P/V in LDS ----------------
__global__ __launch_bounds__(256) void attn_local3(const bf16* __restrict__ qL,
                                                   const bf16* __restrict__ kL,
                                                   const bf16* __restrict__ vL,
                                                   bf16* __restrict__ a){
  __shared__ char vt[16*72];        // V^T fp8 [16 ch][64 tok + 8 pad]
  __shared__ char pb[4][16*72];     // per-wave P fp8
  const int tid = threadIdx.x;
  const int w = tid >> 6, lane = tid & 63;
  const int n16 = lane & 15, quad = lane >> 4;
  const int blk = blockIdx.x;
  const int head = blk & 3, winid = blk >> 2;
  const bf16* Qb = qL + (size_t)blk*1024;
  const bf16* Kb = kL + (size_t)blk*1024;
  const bf16* Vb = vL + (size_t)blk*1024;

  if(tid < 128){
    int tok = tid >> 1, u = tid & 1;
    short8 v = *(const short8*)(Vb + tok*16 + u*8);
#pragma unroll
    for(int i=0;i<8;i+=2){
      int pk = __builtin_amdgcn_cvt_pk_fp8_f32(s2f(((short*)&v)[i]), s2f(((short*)&v)[i+1]), 0, 0);
      vt[(u*8+i)*72 + tok]   = (char)pk;
      vt[(u*8+i+1)*72 + tok] = (char)(pk>>8);
    }
  }
  __syncthreads();

  const int qt = w;
  short8 qf = {0,0,0,0,0,0,0,0};
  if(quad < 2) qf = *(const short8*)(Qb + (qt*16+n16)*16 + quad*8);

  floatx4 sf[4];
#pragma unroll
  for(int kt=0; kt<4; kt++){
    short8 kf = {0,0,0,0,0,0,0,0};
    if(quad < 2) kf = *(const short8*)(Kb + (kt*16+n16)*16 + quad*8);
    floatx4 z = (floatx4){0.f,0.f,0.f,0.f};
    sf[kt] = __builtin_amdgcn_mfma_f32_16x16x32_bf16(qf, kf, z, 0, 0, 0);
  }

  float mx[4] = {-1e30f,-1e30f,-1e30f,-1e30f};
#pragma unroll
  for(int kt=0; kt<4; kt++)
#pragma unroll
    for(int r=0;r<4;r++) mx[r] = fmaxf(mx[r], sf[kt][r]);
#pragma unroll
  for(int r=0;r<4;r++){
    mx[r] = fmaxf(mx[r], __shfl_xor(mx[r], 1, 64));
    mx[r] = fmaxf(mx[r], __shfl_xor(mx[r], 2, 64));
    mx[r] = fmaxf(mx[r], __shfl_xor(mx[r], 4, 64));
    mx[r] = fmaxf(mx[r], __shfl_xor(mx[r], 8, 64));
    mx[r] = -mx[r]*SC2;
  }
  float l[4] = {0.f,0.f,0.f,0.f};
  char* pbw = &pb[w][0];
#pragma unroll
  for(int kt=0; kt<4; kt++){
    float p0 = exp2f(__fmaf_rn(sf[kt][0], SC2, mx[0]));
    float p1 = exp2f(__fmaf_rn(sf[kt][1], SC2, mx[1]));
    float p2 = exp2f(__fmaf_rn(sf[kt][2], SC2, mx[2]));
    float p3 = exp2f(__fmaf_rn(sf[kt][3], SC2, mx[3]));
    l[0]+=p0; l[1]+=p1; l[2]+=p2; l[3]+=p3;
    int pka = __builtin_amdgcn_cvt_pk_fp8_f32(p0, p1, 0, 0);
    int pkb = __builtin_amdgcn_cvt_pk_fp8_f32(p2, p3, 0, 0);
    char* base = pbw + kt*16 + n16;
    base[(quad*4+0)*72] = (char)pka;
    base[(quad*4+1)*72] = (char)(pka>>8);
    base[(quad*4+2)*72] = (char)pkb;
    base[(quad*4+3)*72] = (char)(pkb>>8);
  }
#pragma unroll
  for(int r=0;r<4;r++){
    l[r] += __shfl_xor(l[r], 1, 64);
    l[r] += __shfl_xor(l[r], 2, 64);
    l[r] += __shfl_xor(l[r], 4, 64);
    l[r] += __shfl_xor(l[r], 8, 64);
  }

  floatx4 of = (floatx4){0.f,0.f,0.f,0.f};
#pragma unroll
  for(int kb=0; kb<2; kb++){
    long pf  = *(long*)&pbw[n16*72 + kb*32 + quad*8];
    long vfb = *(long*)&vt [n16*72 + kb*32 + quad*8];
    of = __builtin_amdgcn_mfma_f32_16x16x32_fp8_fp8(pf, vfb, of, 0, 0, 0);
  }

  const int wj = winid & 15, wi = (winid >> 4) & 15, b = winid >> 8;
  const int ooff = head*16;
#pragma unroll
  for(int r=0;r<4;r++){
    int pos = qt*16 + quad*4 + r;
    int h = wi*8 + (pos>>3), ww = wj*8 + (pos&7);
    size_t t = (size_t)b*HW + (size_t)h*Wl + ww;
    a[t*Cc + ooff + n16] = f2b(of[r] / l[r]);
  }
}

// ---------------- grid attention: blk = ginst*4 + head, L=256, fp8 P/V in LDS ----------------
__global__ __launch_bounds__(256) void attn_grid3(const bf16* __restrict__ qG,
                                                  const bf16* __restrict__ kG,
                                                  const bf16* __restrict__ vG,
                                                  bf16* __restrict__ a){
  __shared__ char vt[16*264];       // V^T fp8 [16 ch][256 tok + 8 pad]
  __shared__ char pb[4][16*264];    // per-wave P fp8
  const int tid = threadIdx.x;
  const int w = tid >> 6, lane = tid & 63;
  const int n16 = lane & 15, quad = lane >> 4;
  const int blk = blockIdx.x;
  const int head = blk & 3, ginst = blk >> 2;
  const bf16* Qb = qG + (size_t)blk*4096;
  const bf16* Kb = kG + (size_t)blk*4096;
  const bf16* Vb = vG + (size_t)blk*4096;

#pragma unroll
  for(int it=0; it<2; it++){
    int chunk = it*256 + tid;
    int tok = chunk >> 1, u = chunk & 1;
    short8 v = *(const short8*)(Vb + tok*16 + u*8);
#pragma unroll
    for(int i=0;i<8;i+=2){
      int pk = __builtin_amdgcn_cvt_pk_fp8_f32(s2f(((short*)&v)[i]), s2f(((short*)&v)[i+1]), 0, 0);
      vt[(u*8+i)*264 + tok]   = (char)pk;
      vt[(u*8+i+1)*264 + tok] = (char)(pk>>8);
    }
  }
  __syncthreads();

  const int sj = ginst & 7, si = (ginst >> 3) & 7, b = ginst >> 6;
  const int ooff = 64 + head*16;
  char* pbw = &pb[w][0];

#pragma unroll
  for(int qi=0; qi<4; qi++){
    int qt = w*4 + qi;
    short8 qf = {0,0,0,0,0,0,0,0};
    if(quad < 2) qf = *(const short8*)(Qb + (qt*16+n16)*16 + quad*8);

    floatx4 sf[16];
#pragma unroll
    for(int kt=0; kt<16; kt++){
      short8 kf = {0,0,0,0,0,0,0,0};
      if(quad < 2) kf = *(const short8*)(Kb + (kt*16+n16)*16 + quad*8);
      floatx4 z = (floatx4){0.f,0.f,0.f,0.f};
      sf[kt] = __builtin_amdgcn_mfma_f32_16x16x32_bf16(qf, kf, z, 0, 0, 0);
    }

    float mx[4] = {-1e30f,-1e30f,-1e30f,-1e30f};
#pragma unroll
    for(int kt=0; kt<16; kt++)
#pragma unroll
      for(int r=0;r<4;r++) mx[r] = fmaxf(mx[r], sf[kt][r]);
#pragma unroll
    for(int r=0;r<4;r++){
      mx[r] = fmaxf(mx[r], __shfl_xor(mx[r], 1, 64));
      mx[r] = fmaxf(mx[r], __shfl_xor(mx[r], 2, 64));
      mx[r] = fmaxf(mx[r], __shfl_xor(mx[r], 4, 64));
      mx[r] = fmaxf(mx[r], __shfl_xor(mx[r], 8, 64));
      mx[r] = -mx[r]*SC2;
    }
    float l[4] = {0.f,0.f,0.f,0.f};
#pragma unroll
    for(int kt=0; kt<16; kt++){
      float p0 = exp2f(__fmaf_rn(sf[kt][0], SC2, mx[0]));
      float p1 = exp2f(__fmaf_rn(sf[kt][1], SC2, mx[1]));
      float p2 = exp2f(__fmaf_rn(sf[kt][2], SC2, mx[2]));
      float p3 = exp2f(__fmaf_rn(sf[kt][3], SC2, mx[3]));
      l[0]+=p0; l[1]+=p1; l[2]+=p2; l[3]+=p3;
      int pka = __builtin_amdgcn_cvt_pk_fp8_f32(p0, p1, 0, 0);
      int pkb = __builtin_amdgcn_cvt_pk_fp8_f32(p2, p3, 0, 0);
      char* base = pbw + kt*16 + n16;
      base[(quad*4+0)*264] = (char)pka;
      base[(quad*4+1)*264] = (char)(pka>>8);
      base[(quad*4+2)*264] = (char)pkb;
      base[(quad*4+3)*264] = (char)(pkb>>8);
    }
#pragma unroll
    for(int r=0;r<4;r++){
      l[r] += __shfl_xor(l[r], 1, 64);
      l[r] += __shfl_xor(l[r], 2, 64);
      l[r] += __shfl_xor(l[r], 4, 64);
      l[r] += __shfl_xor(l[r], 8, 64);
    }

    floatx4 of = (floatx4){0.f,0.f,0.f,0.f};
#pragma unroll
    for(int kb=0; kb<8; kb++){
      long pf  = *(long*)&pbw[n16*264 + kb*32 + quad*8];
      long vfb = *(long*)&vt [n16*264 + kb*32 + quad*8];
      of = __builtin_amdgcn_mfma_f32_16x16x32_fp8_fp8(pf, vfb, of, 0, 0, 0);
    }

#pragma unroll
    for(int r=0;r<4;r++){
      int pos = qt*16 + quad*4 + r;
      int h = (pos>>4)*8 + si, ww = (pos&15)*8 + sj;
      size_t t = (size_t)b*HW + (size_t)h*Wl + ww;
      a[t*Cc + ooff + n16] = f2b(of[r] / l[r]);
    }
  }
}

// ---------------- (B, HW, C) -> (B, C, HW) transpose, bf16 -> fp32 out ----------------
__global__ __launch_bounds__(256) void transpose_kernel(const bf16* __restrict__ xf,
                                                        float* __restrict__ out){
  __shared__ bf16 tile[32][33];
  int t0 = blockIdx.x*32, c0 = blockIdx.y*32, b = blockIdx.z;
  int x = threadIdx.x, y = threadIdx.y;   // 32, 8
  const bf16* src = xf + (size_t)b*HW*Cc;
  float* dst = out + (size_t)b*Cc*HW;
#pragma unroll
  for(int i=0;i<4;i++)
    tile[y*4+i][x] = src[(size_t)(t0 + y*4+i)*Cc + c0 + x];
  __syncthreads();
#pragma unroll
  for(int i=0;i<4;i++)
    dst[(size_t)(c0 + y*4+i)*HW + t0 + x] = b2f(tile[x][y*4+i]);
}

extern "C" void kernel_launch(void* const* d_in, const int* in_sizes, int n_in,
                              void* d_out, int out_size, void* d_ws, size_t ws_size,
                              hipStream_t stream) {
  const float* x       = (const float*)d_in[0];
  const float* conv_w  = (const float*)d_in[1];
  const float* conv_b  = (const float*)d_in[2];
  const float* norm1_w = (const float*)d_in[3];
  const float* norm1_b = (const float*)d_in[4];
  const float* wqkv    = (const float*)d_in[5];
  const float* proj_w  = (const float*)d_in[6];
  const float* proj_b  = (const float*)d_in[7];
  const float* norm2_w = (const float*)d_in[8];
  const float* norm2_b = (const float*)d_in[9];
  const float* fc1_w   = (const float*)d_in[10];
  const float* fc1_b   = (const float*)d_in[11];
  const float* fc2_w   = (const float*)d_in[12];
  const float* fc2_b   = (const float*)d_in[13];
  const float* ls1     = (const float*)d_in[14];
  const float* ls2     = (const float*)d_in[15];
  float* out = (float*)d_out;

  char* ws = (char*)d_ws;
  float* xt = (float*)ws;                                        // 64 MiB fp32 residual
  bf16*  sh = (bf16*)(ws + (size_t)NT*Cc*4);                     // 32 MiB: xn -> a -> xn2 -> xt_final
  bf16*  qh = (bf16*)(ws + (size_t)NT*Cc*4 + (size_t)NT*Cc*2);   // 128 MiB: qkv buffers, then h1
  bf16*  wt = (bf16*)(ws + (size_t)NT*Cc*4 + (size_t)NT*Cc*2 + (size_t)NT*512*2);
  bf16* qkvT = wt;            // 384 x 128
  bf16* projT= wt + 49152;    // 128 x 128
  bf16* fc1T = wt + 65536;    // 512 x 128
  bf16* fc2T = wt + 131072;   // 128 x 512

  transpose_all<<<196608/256, 256, 0, stream>>>(wqkv, proj_w, fc1_w, fc2_w,
                                                qkvT, projT, fc1T, fc2T);
  conv_kernel<<<Bn*8*Hh, 256, 0, stream>>>(x, conv_w, conv_b, xt);
  ln_kernel<<<NT/4, 256, 0, stream>>>(xt, norm1_w, norm1_b, sh);
  // qkv GEMM scatters into qL,qG,kL,kG,vL,vG (6 x 16 MiB at qh)
  mfma_gemm<0><<<dim3(384/64, NT/128), 256, 0, stream>>>(sh, qkvT, nullptr, qh, nullptr, nullptr, 384, 128);
  attn_grid3<<<2048, 256, 0, stream>>>(qh + (size_t)1*REG, qh + (size_t)3*REG, qh + (size_t)5*REG, sh);
  attn_local3<<<8192, 256, 0, stream>>>(qh + (size_t)0*REG, qh + (size_t)2*REG, qh + (size_t)4*REG, sh);
  mfma_gemm<2><<<dim3(128/64, NT/128), 256, 0, stream>>>(sh, projT, proj_b, nullptr, xt, ls1, 128, 128);
  ln_kernel<<<NT/4, 256, 0, stream>>>(xt, norm2_w, norm2_b, sh);
  mfma_gemm<1><<<dim3(512/64, NT/128), 256, 0, stream>>>(sh, fc1T, fc1_b, qh, nullptr, nullptr, 512, 128);
  mfma_gemm<3><<<dim3(128/64, NT/128), 256, 0, stream>>>(qh, fc2T, fc2_b, sh, xt, ls2, 128, 512);
  transpose_kernel<<<dim3(HW/32, Cc/32, Bn), dim3(32,8), 0, stream>>>(sh, out);
}